// Round 13
// baseline (8084.003 us; speedup 1.0000x reference)
//
#include <hip/hip_runtime.h>
#include <cstddef>
#include <climits>

#define BB 32
#define TT 512
#define HH 512
#define NBLK 256
#define NTHR 512
#define YD 16  // y0 ring depth
#define AG __HIP_MEMORY_SCOPE_AGENT

// ---------------------------------------------------------------------------
// Persistent GRU, round 12 = round 11 + XCD-local group flags + combined polls.
//
//   Arrive: __syncthreads (vmcnt drain -> all block stores committed), then
//     tid0 stores the phase number TWICE: plain store to the LOCAL slot
//     (dirty in this XCD's L2 -- visible to same-XCD sc0 loads in ~L2 RTT;
//     exact mechanism of the proven round-6 data protocol) and sc1 store to
//     the GLOBAL slot (L3; cross-XCD gates + safety net).
//   Own-group poll: lane L reads local slot[L&31] sc0 every spin; every 16th
//     spin also reads the global slot (max) -> if sc0-on-flags were broken we
//     degrade gracefully instead of deadlocking. Fallback mode: global only.
//   SYNC1 (one combined ballot): own >= 2t  AND  peer gate
//     (L1: peer >= 2t+2 => y0[t] complete; L0,t>=YD: peer >= 2t-31 => ring
//     slot free -- checked early at A-start, stricter than needed = safe).
//   SYNC2: own >= 2t+1 (rh/uu ready), overlapped by cand x-half partials.
//   Liveness: arrivals unconditional every phase incl. the last; waits only
//     on past arrivals -> no circular wait. WAR: all state stores sit after
//     the wait proving readers done (same ordering as rounds 8-11).
//   Data protocol (round 6 proven): XCD-local h/rh/uu = plain stores + sc0
//     loads; cross-XCD y0 = sc1 (L3); x/W/b plain cached. Fallback: all sc1.
//
// ws (floats): h0@0[16384] h1@16384[16384] ctrl(int)@32768[64]
//   barb(int)@32832[192] gslot(int)@33024[8*32] lslot(int)@33280[8*32]
//   (zero region ends @33536)
//   y0@36864[16][32][512] rh@299008[2][32][512] uu@331776[2][32][512]
// ---------------------------------------------------------------------------

__device__ __forceinline__ float2 ld2_sc1(const float* p) {
    double d = __hip_atomic_load((const double*)p, __ATOMIC_RELAXED, AG);
    return __builtin_bit_cast(float2, d);
}
__device__ __forceinline__ void st1_sc1(float* p, float v) {
    __hip_atomic_store(p, v, __ATOMIC_RELAXED, AG);
}
__device__ __forceinline__ int ldi_sc1(const int* p) {
    return __hip_atomic_load(p, __ATOMIC_RELAXED, AG);
}
__device__ __forceinline__ void sti_sc1(int* p, int v) {
    __hip_atomic_store(p, v, __ATOMIC_RELAXED, AG);
}
// Plain store (dirty local L2) -- arrival flag, round-6 data-store mechanism.
__device__ __forceinline__ void st_plain(int* p, int v) {
    asm volatile("global_store_dword %0, %1, off" : : "v"(p), "v"(v) : "memory");
}
// L1-bypassing load served by the local L2 (round-6 proven).
__device__ __forceinline__ int ld_sc0i(const int* p) {
    int r;
    asm volatile("global_load_dword %0, %1, off sc0\n\ts_waitcnt vmcnt(0)"
                 : "=v"(r) : "v"(p) : "memory");
    return r;
}

// Four 8B loads, L1-bypass / local-L2 hit (round-6 proven).
__device__ __forceinline__ void ld2_sc0_x4(const float* p0, const float* p1,
                                           const float* p2, const float* p3,
                                           float2& v0, float2& v1,
                                           float2& v2, float2& v3) {
    asm volatile(
        "global_load_dwordx2 %0, %4, off sc0\n\t"
        "global_load_dwordx2 %1, %5, off sc0\n\t"
        "global_load_dwordx2 %2, %6, off sc0\n\t"
        "global_load_dwordx2 %3, %7, off sc0\n\t"
        "s_waitcnt vmcnt(0)"
        : "=v"(v0), "=v"(v1), "=v"(v2), "=v"(v3)
        : "v"(p0), "v"(p1), "v"(p2), "v"(p3)
        : "memory");
}

// Reduce 4 accs over 64 lanes; lane ends with total of acc[lane&3].
__device__ __forceinline__ float red4(float a0, float a1, float a2, float a3,
                                      int lane) {
    const bool b1 = lane & 1, b2 = lane & 2;
    float p0 = (b1 ? a1 : a0) + __shfl_xor((b1 ? a0 : a1), 1, 64);
    float p1 = (b1 ? a3 : a2) + __shfl_xor((b1 ? a2 : a3), 1, 64);
    float r = (b2 ? p1 : p0) + __shfl_xor((b2 ? p0 : p1), 2, 64);
    r += __shfl_xor(r, 4, 64);
    r += __shfl_xor(r, 8, 64);
    r += __shfl_xor(r, 16, 64);
    r += __shfl_xor(r, 32, 64);
    return r;
}
// Reduce 2 accs; lane ends with total of acc[lane&1].
__device__ __forceinline__ float red2(float a0, float a1, int lane) {
    const bool b1 = lane & 1;
    float r = (b1 ? a1 : a0) + __shfl_xor((b1 ? a0 : a1), 1, 64);
    r += __shfl_xor(r, 2, 64);
    r += __shfl_xor(r, 4, 64);
    r += __shfl_xor(r, 8, 64);
    r += __shfl_xor(r, 16, 64);
    r += __shfl_xor(r, 32, 64);
    return r;
}

// Global 2-level tree barrier (sc1 RMW) - prologue / self-org only (proven).
__device__ __forceinline__ void gbar(int* barb, int bid, int nbar) {
    __syncthreads();
    if (threadIdx.x == 0) {
        __hip_atomic_fetch_add(&barb[(bid & 31) * 4], 1, __ATOMIC_RELAXED, AG);
        if (bid < 32) {
            const int lt = nbar * 8;
            while (__hip_atomic_load(&barb[bid * 4], __ATOMIC_RELAXED, AG) < lt)
                __builtin_amdgcn_s_sleep(1);
            __hip_atomic_fetch_add(&barb[128], 1, __ATOMIC_RELAXED, AG);
        }
        const int rt = nbar * 32;
        while (__hip_atomic_load(&barb[128], __ATOMIC_RELAXED, AG) < rt)
            __builtin_amdgcn_s_sleep(1);
    }
    __syncthreads();
}

// Combined ballot poll: own-group flags (local sc0 fast path + periodic
// global sc1 truth mix-in) AND optional peer-group gate (global sc1).
__device__ __forceinline__ void poll2(const int* lown, const int* gown,
                                      const int* gpeer, int need_own,
                                      bool peer_chk, int need_peer, int fb) {
    if (threadIdx.x < 64) {
        const int L = threadIdx.x & 31;
        int spins = 0;
        for (;;) {
            int v;
            if (fb) {
                v = ldi_sc1(&gown[L]);
            } else {
                v = ld_sc0i(&lown[L]);
                if ((spins & 15) == 15) {
                    const int gv = ldi_sc1(&gown[L]);
                    v = v > gv ? v : gv;
                }
            }
            bool ok = v >= need_own;
            if (peer_chk) ok = ok && (ldi_sc1(&gpeer[L]) >= need_peer);
            if (__ballot(ok) == ~0ull) break;
            ++spins;
            __builtin_amdgcn_s_sleep(1);
        }
    }
    __syncthreads();
}

// Arrive: drain block stores, then dual flag store (local plain + global sc1).
__device__ __forceinline__ void arrive2(int* lslot, int* gslot, int val, int fb) {
    __syncthreads();  // compiler drains vmcnt(0) before s_barrier
    if (threadIdx.x == 0) {
        if (!fb) st_plain(lslot, val);
        sti_sc1(gslot, val);
    }
}

__global__ __launch_bounds__(NTHR, 2) void rnn_persist(
    const float* __restrict__ x, const int* __restrict__ seq_lens,
    const float* __restrict__ Wg, const float* __restrict__ bg,
    const float* __restrict__ Wc, const float* __restrict__ bc,
    float* __restrict__ out, float* __restrict__ ws) {
    __shared__ float ldsA[8][1024];  // per batch: [input 512 | h 512]
    __shared__ float ldsB[8][512];   // rh rows
    __shared__ float ldsU[8][512];   // uu rows
    __shared__ int shi[4];

    float* h0 = ws;
    float* h1 = ws + 16384;
    int* ctrl = (int*)(ws + 32768);   // pools[16], order@16, fb@17, map@18..33
    int* barb = (int*)(ws + 32832);   // global tree (prologue only)
    int* gslot = (int*)(ws + 33024);  // 8 groups x 32 ints (sc1 flags)
    int* lslot = (int*)(ws + 33280);  // 8 groups x 32 ints (local flags)
    float* y0 = ws + 36864;           // [YD][BB][HH]
    float* rh = ws + 299008;
    float* uu = ws + 331776;

    const int tid = threadIdx.x, bid = blockIdx.x;
    const int w = tid >> 6, lane = tid & 63;

    // ---- self-organization by physical XCD (rounds 6/8/11 proven) ----
    if (tid == 0) {
        int xcc;
        asm volatile("s_getreg_b32 %0, hwreg(HW_REG_XCC_ID)" : "=s"(xcc));
        xcc &= 15;
        int slot = __hip_atomic_fetch_add(&ctrl[xcc], 1, __ATOMIC_RELAXED, AG);
        shi[0] = xcc; shi[1] = slot;
    }
    __syncthreads();
    gbar(barb, bid, 1);
    if (tid == 0) {
        if (ldi_sc1(&ctrl[shi[0]]) != 32)
            sti_sc1(&ctrl[17], 1);
        if (shi[1] == 0) {
            int ord = __hip_atomic_fetch_add(&ctrl[16], 1, __ATOMIC_RELAXED, AG);
            sti_sc1(&ctrl[18 + shi[0]], ord + 1);
        }
    }
    gbar(barb, bid, 2);
    if (tid == 0) {
        int fbf = ldi_sc1(&ctrl[17]);
        if (ldi_sc1(&ctrl[16]) != 8) fbf = 1;
        int xi, sl;
        if (fbf) { xi = bid & 7; sl = bid >> 3; }
        else     { xi = ldi_sc1(&ctrl[18 + shi[0]]) - 1; sl = shi[1]; }
        shi[2] = fbf; shi[3] = xi; shi[1] = sl;
    }
    __syncthreads();
    const int fb = shi[2];
    const int xcd = shi[3];   // logical group id 0..7
    const int slot = shi[1];  // 0..31 within group
    const int l = xcd & 1;
    const int g = xcd >> 1;
    const int b0 = g * 8;
    const int gj0 = slot * 32 + w * 4;
    const int cm0 = slot * 16 + w * 2;
    const int kb = 2 * lane;

    float* __restrict__ hl = l ? h1 : h0;
    float* __restrict__ rhl = rh + (size_t)l * (BB * HH);
    float* __restrict__ uul = uu + (size_t)l * (BB * HH);
    int* gmy = gslot + xcd * 32;
    int* lmy = lslot + xcd * 32;
    int* gpeer = gslot + (g * 2 + (1 - l)) * 32;

    // ---- one-time weight load into registers (original layout) ----
    float2 wg[4][8];
#pragma unroll
    for (int c = 0; c < 4; ++c)
#pragma unroll
        for (int i = 0; i < 8; ++i) {
            const size_t r = (size_t)l * 1024 + kb + (i << 7);
            wg[c][i].x = Wg[r * 1024 + gj0 + c];
            wg[c][i].y = Wg[(r + 1) * 1024 + gj0 + c];
        }
    float2 wc[2][8];
#pragma unroll
    for (int c = 0; c < 2; ++c)
#pragma unroll
        for (int i = 0; i < 8; ++i) {
            const size_t r = (size_t)l * 1024 + kb + (i << 7);
            wc[c][i].x = Wc[r * 512 + cm0 + c];
            wc[c][i].y = Wc[(r + 1) * 512 + cm0 + c];
        }
    const float bgj = bg[l * 1024 + gj0 + (lane & 3)];
    const float bcm = bc[l * 512 + cm0 + (lane & 1)];
    int sl_[8];
#pragma unroll
    for (int i = 0; i < 8; ++i) sl_[i] = seq_lens[b0 + i];

    for (int t = 0; t < TT; ++t) {
        // ======= SYNC1: own end-of-B(t-1) AND peer gate, one combined poll =======
        // L1 peer: y0[t] complete <=> all L0 slots >= 2t+2.
        // L0 peer (t>=YD): ring slot free <=> all L1 slots >= 2t-31 (early=safe).
        {
            const bool pc = (l == 1) || (t >= YD);
            const int np = (l == 1) ? (2 * t + 2) : (2 * t - 31);
            poll2(lmy, gmy, gpeer, 2 * t, pc, np, fb);
        }
        // ================= phase A: gates =================
        {   // stage full row [in | h] of batch b0+w
            const int b = b0 + w;
            const float* inrow = l ? (y0 + ((size_t)((t & (YD - 1)) * BB + b)) * HH)
                                   : (x + ((size_t)b * TT + t) * HH);
            const float* hrow = hl + (size_t)b * HH;
            float2 vi[4], vh[4];
            if (l == 0) {
#pragma unroll
                for (int i = 0; i < 4; ++i)
                    vi[i] = *(const float2*)(inrow + kb + (i << 7));
            } else {
#pragma unroll
                for (int i = 0; i < 4; ++i)
                    vi[i] = ld2_sc1(inrow + kb + (i << 7));
            }
            if (fb) {
#pragma unroll
                for (int i = 0; i < 4; ++i)
                    vh[i] = ld2_sc1(hrow + kb + (i << 7));
            } else {
                ld2_sc0_x4(hrow + kb, hrow + kb + 128, hrow + kb + 256,
                           hrow + kb + 384, vh[0], vh[1], vh[2], vh[3]);
            }
#pragma unroll
            for (int i = 0; i < 4; ++i) {
                *(float2*)&ldsA[w][kb + (i << 7)] = vi[i];
                *(float2*)&ldsA[w][512 + kb + (i << 7)] = vh[i];
            }
        }
        __syncthreads();
#pragma unroll 2
        for (int bi = 0; bi < 8; ++bi) {
            float s0 = 0, s1 = 0, s2 = 0, s3 = 0;
#pragma unroll
            for (int i = 0; i < 8; ++i) {
                const float2 v = *(const float2*)&ldsA[bi][kb + (i << 7)];
                s0 = fmaf(v.y, wg[0][i].y, fmaf(v.x, wg[0][i].x, s0));
                s1 = fmaf(v.y, wg[1][i].y, fmaf(v.x, wg[1][i].x, s1));
                s2 = fmaf(v.y, wg[2][i].y, fmaf(v.x, wg[2][i].x, s2));
                s3 = fmaf(v.y, wg[3][i].y, fmaf(v.x, wg[3][i].x, s3));
            }
            const float sum = red4(s0, s1, s2, s3, lane);
            if (lane < 4) {
                const int j = gj0 + lane;
                const int b = b0 + bi;
                const float gg = 1.0f / (1.0f + __expf(-(sum + bgj)));
                if (gj0 < HH) {
                    const float val = gg * ldsA[bi][512 + j];
                    if (fb) st1_sc1(rhl + (size_t)b * HH + j, val);
                    else rhl[(size_t)b * HH + j] = val;
                } else {
                    if (fb) st1_sc1(uul + (size_t)b * HH + (j - HH), gg);
                    else uul[(size_t)b * HH + (j - HH)] = gg;
                }
            }
        }
        arrive2(&lmy[slot], &gmy[slot], 2 * t + 1, fb);

        // ================= phase B: candidate + update =================
        // cand x-half partial accs (in-row still in ldsA; overlaps peer skew)
        float aB0[8], aB1[8];
#pragma unroll
        for (int bi = 0; bi < 8; ++bi) {
            float s0 = 0, s1 = 0;
#pragma unroll
            for (int i = 0; i < 4; ++i) {
                const float2 v = *(const float2*)&ldsA[bi][kb + (i << 7)];
                s0 = fmaf(v.y, wc[0][i].y, fmaf(v.x, wc[0][i].x, s0));
                s1 = fmaf(v.y, wc[1][i].y, fmaf(v.x, wc[1][i].x, s1));
            }
            aB0[bi] = s0; aB1[bi] = s1;
        }
        // ======= SYNC2: own end-of-A(t) =======
        poll2(lmy, gmy, gpeer, 2 * t + 1, false, 0, fb);
        {   // stage rh + uu rows of batch b0+w
            const int b = b0 + w;
            const float* rrow = rhl + (size_t)b * HH;
            const float* urow = uul + (size_t)b * HH;
            float2 vr[4], vu[4];
            if (fb) {
#pragma unroll
                for (int i = 0; i < 4; ++i) {
                    vr[i] = ld2_sc1(rrow + kb + (i << 7));
                    vu[i] = ld2_sc1(urow + kb + (i << 7));
                }
            } else {
                ld2_sc0_x4(rrow + kb, rrow + kb + 128, rrow + kb + 256,
                           rrow + kb + 384, vr[0], vr[1], vr[2], vr[3]);
                ld2_sc0_x4(urow + kb, urow + kb + 128, urow + kb + 256,
                           urow + kb + 384, vu[0], vu[1], vu[2], vu[3]);
            }
#pragma unroll
            for (int i = 0; i < 4; ++i) {
                *(float2*)&ldsB[w][kb + (i << 7)] = vr[i];
                *(float2*)&ldsU[w][kb + (i << 7)] = vu[i];
            }
        }
        __syncthreads();
#pragma unroll
        for (int bi = 0; bi < 8; ++bi) {
            float s0 = aB0[bi], s1 = aB1[bi];
#pragma unroll
            for (int i = 0; i < 4; ++i) {
                const float2 v = *(const float2*)&ldsB[bi][kb + (i << 7)];
                s0 = fmaf(v.y, wc[0][i + 4].y, fmaf(v.x, wc[0][i + 4].x, s0));
                s1 = fmaf(v.y, wc[1][i + 4].y, fmaf(v.x, wc[1][i + 4].x, s1));
            }
            const float sum = red2(s0, s1, lane);
            if (lane < 2) {
                const int m = cm0 + lane;
                const int b = b0 + bi;
                const float cv = tanhf(sum + bcm);
                const float u = ldsU[bi][m];
                const float hold = ldsA[bi][512 + m];
                const bool act = t < sl_[bi];
                const float hn = u * hold + (1.0f - u) * cv;
                const float hstore = act ? hn : hold;
                if (fb) st1_sc1(hl + (size_t)b * HH + m, hstore);
                else hl[(size_t)b * HH + m] = hstore;
                const float yv = act ? hn : 0.0f;
                if (l == 0)
                    st1_sc1(y0 + ((size_t)((t & (YD - 1)) * BB + b)) * HH + m, yv);
                else
                    out[((size_t)b * TT + t) * HH + m] = yv;
            }
        }
        arrive2(&lmy[slot], &gmy[slot], 2 * t + 2, fb);
    }
}

extern "C" void kernel_launch(void* const* d_in, const int* in_sizes, int n_in,
                              void* d_out, int out_size, void* d_ws, size_t ws_size,
                              hipStream_t stream) {
    const float* x = (const float*)d_in[0];
    const int* seq_lens = (const int*)d_in[1];
    const float* Wg = (const float*)d_in[2];
    const float* bg = (const float*)d_in[3];
    const float* Wc = (const float*)d_in[4];
    const float* bc = (const float*)d_in[5];
    float* out = (float*)d_out;
    float* ws = (float*)d_ws;

    // zero h0/h1 + ctrl + prologue tree + both slot arrays every launch
    (void)hipMemsetAsync(ws, 0, 33536 * sizeof(float), stream);

    rnn_persist<<<NBLK, NTHR, 0, stream>>>(x, seq_lens, Wg, bg, Wc, bc, out, ws);
}

// Round 14
// 5787.881 us; speedup vs baseline: 1.3967x; 1.3967x over previous
//
#include <hip/hip_runtime.h>
#include <cstddef>

#define BB 32
#define TT 512
#define HH 512
#define NBLK 256
#define NTHR 512
#define YD 16  // y0 ring depth
#define AG __HIP_MEMORY_SCOPE_AGENT

// ---------------------------------------------------------------------------
// Persistent GRU, round 13 = round 11 (best verified: 6.39 ms) +
//   (1) v_pk_fma_f32 packed-f32 dot loops (we are issue-bound: halves the
//       FMA instruction count; FLOPs unchanged),
//   (2) u staged as the block's own 16 cols only (ldsU[8][16], one scalar
//       sc0 load per wave) instead of the full 512-wide row.
// Sync design byte-identical to round 11:
//   Arrive: __syncthreads (vmcnt drain) then one relaxed sc1 store of the
//     phase number into this block's slot — every phase incl. the last.
//   Waits: wave-0 ballot-polls 32 slot words (own group or peer group).
//     L1 A(t): peer >= 2t+2. L0 B(t>=YD): peer >= 2t-31. Own: 2t / 2t+1.
//   Split-phase overlap: stage in-row -> x-half partials -> own-poll ->
//     stage h -> finish; cand x-half partials before SYNC2.
//   Data protocol (round 6 proven): XCD-local h/rh/uu plain stores + sc0
//     loads (local L2); cross-XCD y0 sc1 (L3); x/W/b plain cached.
//   Fallback (bad XCC mapping): logical groups, everything sc1.
//
// ws (floats): h0@0[16384] h1@16384[16384] ctrl(int)@32768[64]
//   barb(int)@32832[192] pslot(int)@33024[8 groups x 32]
//   (zero region ends @33280)
//   y0@36864[16][32][512] rh@299008[2][32][512] uu@331776[2][32][512]
// ---------------------------------------------------------------------------

__device__ __forceinline__ float2 ld2_sc1(const float* p) {
    double d = __hip_atomic_load((const double*)p, __ATOMIC_RELAXED, AG);
    return __builtin_bit_cast(float2, d);
}
__device__ __forceinline__ float ld1f_sc1(const float* p) {
    return __hip_atomic_load(p, __ATOMIC_RELAXED, AG);
}
__device__ __forceinline__ void st1_sc1(float* p, float v) {
    __hip_atomic_store(p, v, __ATOMIC_RELAXED, AG);
}
__device__ __forceinline__ int ldi_sc1(const int* p) {
    return __hip_atomic_load(p, __ATOMIC_RELAXED, AG);
}
__device__ __forceinline__ void sti_sc1(int* p, int v) {
    __hip_atomic_store(p, v, __ATOMIC_RELAXED, AG);
}

// Packed f32 FMA: d = a*b + c on both halves, one instruction (CDNA2+).
__device__ __forceinline__ float2 pkfma(float2 a, float2 b, float2 c) {
    float2 d;
    asm("v_pk_fma_f32 %0, %1, %2, %3" : "=v"(d) : "v"(a), "v"(b), "v"(c));
    return d;
}

// Scalar load, L1-bypass / local-L2 hit (round-6 proven mechanism).
__device__ __forceinline__ float ld_sc0f(const float* p) {
    float r;
    asm volatile("global_load_dword %0, %1, off sc0\n\ts_waitcnt vmcnt(0)"
                 : "=v"(r) : "v"(p) : "memory");
    return r;
}

// Four 8B loads, L1-bypass / local-L2 hit (round-6 proven).
__device__ __forceinline__ void ld2_sc0_x4(const float* p0, const float* p1,
                                           const float* p2, const float* p3,
                                           float2& v0, float2& v1,
                                           float2& v2, float2& v3) {
    asm volatile(
        "global_load_dwordx2 %0, %4, off sc0\n\t"
        "global_load_dwordx2 %1, %5, off sc0\n\t"
        "global_load_dwordx2 %2, %6, off sc0\n\t"
        "global_load_dwordx2 %3, %7, off sc0\n\t"
        "s_waitcnt vmcnt(0)"
        : "=v"(v0), "=v"(v1), "=v"(v2), "=v"(v3)
        : "v"(p0), "v"(p1), "v"(p2), "v"(p3)
        : "memory");
}

// Reduce 4 accs over 64 lanes; lane ends with total of acc[lane&3].
__device__ __forceinline__ float red4(float a0, float a1, float a2, float a3,
                                      int lane) {
    const bool b1 = lane & 1, b2 = lane & 2;
    float p0 = (b1 ? a1 : a0) + __shfl_xor((b1 ? a0 : a1), 1, 64);
    float p1 = (b1 ? a3 : a2) + __shfl_xor((b1 ? a2 : a3), 1, 64);
    float r = (b2 ? p1 : p0) + __shfl_xor((b2 ? p0 : p1), 2, 64);
    r += __shfl_xor(r, 4, 64);
    r += __shfl_xor(r, 8, 64);
    r += __shfl_xor(r, 16, 64);
    r += __shfl_xor(r, 32, 64);
    return r;
}
// Reduce 2 accs; lane ends with total of acc[lane&1].
__device__ __forceinline__ float red2(float a0, float a1, int lane) {
    const bool b1 = lane & 1;
    float r = (b1 ? a1 : a0) + __shfl_xor((b1 ? a0 : a1), 1, 64);
    r += __shfl_xor(r, 2, 64);
    r += __shfl_xor(r, 4, 64);
    r += __shfl_xor(r, 8, 64);
    r += __shfl_xor(r, 16, 64);
    r += __shfl_xor(r, 32, 64);
    return r;
}

// Global 2-level tree barrier (sc1 RMW) - prologue / self-org only (proven).
__device__ __forceinline__ void gbar(int* barb, int bid, int nbar) {
    __syncthreads();
    if (threadIdx.x == 0) {
        __hip_atomic_fetch_add(&barb[(bid & 31) * 4], 1, __ATOMIC_RELAXED, AG);
        if (bid < 32) {
            const int lt = nbar * 8;
            while (__hip_atomic_load(&barb[bid * 4], __ATOMIC_RELAXED, AG) < lt)
                __builtin_amdgcn_s_sleep(1);
            __hip_atomic_fetch_add(&barb[128], 1, __ATOMIC_RELAXED, AG);
        }
        const int rt = nbar * 32;
        while (__hip_atomic_load(&barb[128], __ATOMIC_RELAXED, AG) < rt)
            __builtin_amdgcn_s_sleep(1);
    }
    __syncthreads();
}

// Ballot-poll until ALL 32 slot words of `slots` reach `need`.
template <int SLP>
__device__ __forceinline__ void poll_slots(int* slots, int need) {
    if (threadIdx.x < 64) {
        for (;;) {
            const int v = __hip_atomic_load(&slots[threadIdx.x & 31],
                                            __ATOMIC_RELAXED, AG);
            if (__ballot(v >= need) == ~0ull) break;
            __builtin_amdgcn_s_sleep(SLP);
        }
    }
    __syncthreads();
}

// Arrive: drain this block's stores, then one sc1 store (no RMW).
__device__ __forceinline__ void arrive(int* myslot, int val) {
    __syncthreads();  // compiler drains vmcnt(0) before s_barrier
    if (threadIdx.x == 0) sti_sc1(myslot, val);
}

__global__ __launch_bounds__(NTHR, 2) void rnn_persist(
    const float* __restrict__ x, const int* __restrict__ seq_lens,
    const float* __restrict__ Wg, const float* __restrict__ bg,
    const float* __restrict__ Wc, const float* __restrict__ bc,
    float* __restrict__ out, float* __restrict__ ws) {
    __shared__ float ldsA[8][1024];  // per batch: [input 512 | h 512]
    __shared__ float ldsB[8][512];   // rh rows
    __shared__ float ldsU[8][16];    // u, block's own 16 cand cols only
    __shared__ int shi[4];

    float* h0 = ws;
    float* h1 = ws + 16384;
    int* ctrl = (int*)(ws + 32768);   // pools[16], order@16, fb@17, map@18..33
    int* barb = (int*)(ws + 32832);   // global tree (prologue only)
    int* pslot = (int*)(ws + 33024);  // 8 groups x 32 ints
    float* y0 = ws + 36864;           // [YD][BB][HH]
    float* rh = ws + 299008;
    float* uu = ws + 331776;

    const int tid = threadIdx.x, bid = blockIdx.x;
    const int w = tid >> 6, lane = tid & 63;

    // ---- self-organization by physical XCD (rounds 6/8/11 proven) ----
    if (tid == 0) {
        int xcc;
        asm volatile("s_getreg_b32 %0, hwreg(HW_REG_XCC_ID)" : "=s"(xcc));
        xcc &= 15;
        int slot = __hip_atomic_fetch_add(&ctrl[xcc], 1, __ATOMIC_RELAXED, AG);
        shi[0] = xcc; shi[1] = slot;
    }
    __syncthreads();
    gbar(barb, bid, 1);
    if (tid == 0) {
        if (ldi_sc1(&ctrl[shi[0]]) != 32)
            sti_sc1(&ctrl[17], 1);
        if (shi[1] == 0) {
            int ord = __hip_atomic_fetch_add(&ctrl[16], 1, __ATOMIC_RELAXED, AG);
            sti_sc1(&ctrl[18 + shi[0]], ord + 1);
        }
    }
    gbar(barb, bid, 2);
    if (tid == 0) {
        int fbf = ldi_sc1(&ctrl[17]);
        if (ldi_sc1(&ctrl[16]) != 8) fbf = 1;
        int xi, sl;
        if (fbf) { xi = bid & 7; sl = bid >> 3; }
        else     { xi = ldi_sc1(&ctrl[18 + shi[0]]) - 1; sl = shi[1]; }
        shi[2] = fbf; shi[3] = xi; shi[1] = sl;
    }
    __syncthreads();
    const int fb = shi[2];
    const int xcd = shi[3];   // logical group id 0..7
    const int slot = shi[1];  // 0..31 within group
    const int l = xcd & 1;
    const int g = xcd >> 1;
    const int b0 = g * 8;
    const int gj0 = slot * 32 + w * 4;
    const int cm0 = slot * 16 + w * 2;
    const int kb = 2 * lane;

    float* __restrict__ hl = l ? h1 : h0;
    float* __restrict__ rhl = rh + (size_t)l * (BB * HH);
    float* __restrict__ uul = uu + (size_t)l * (BB * HH);
    int* myslots = pslot + xcd * 32;
    int* peerslots = pslot + (g * 2 + (1 - l)) * 32;

    // ---- one-time weight load into registers (original layout) ----
    float2 wg[4][8];
#pragma unroll
    for (int c = 0; c < 4; ++c)
#pragma unroll
        for (int i = 0; i < 8; ++i) {
            const size_t r = (size_t)l * 1024 + kb + (i << 7);
            wg[c][i].x = Wg[r * 1024 + gj0 + c];
            wg[c][i].y = Wg[(r + 1) * 1024 + gj0 + c];
        }
    float2 wc[2][8];
#pragma unroll
    for (int c = 0; c < 2; ++c)
#pragma unroll
        for (int i = 0; i < 8; ++i) {
            const size_t r = (size_t)l * 1024 + kb + (i << 7);
            wc[c][i].x = Wc[r * 512 + cm0 + c];
            wc[c][i].y = Wc[(r + 1) * 512 + cm0 + c];
        }
    const float bgj = bg[l * 1024 + gj0 + (lane & 3)];
    const float bcm = bc[l * 512 + cm0 + (lane & 1)];
    int sl_[8];
#pragma unroll
    for (int i = 0; i < 8; ++i) sl_[i] = seq_lens[b0 + i];

    for (int t = 0; t < TT; ++t) {
        // ================= phase A: gates =================
        // L1 gate: y0[t] produced <=> all L0 slots >= 2t+2 (L0 arrived B(t)).
        if (l == 1) poll_slots<2>(peerslots, 2 * t + 2);
        {   // stage in-row of batch b0+w (no group dependency)
            const int b = b0 + w;
            const float* inrow = l ? (y0 + ((size_t)((t & (YD - 1)) * BB + b)) * HH)
                                   : (x + ((size_t)b * TT + t) * HH);
            float2 vi[4];
            if (l == 0) {
#pragma unroll
                for (int i = 0; i < 4; ++i)
                    vi[i] = *(const float2*)(inrow + kb + (i << 7));
            } else {
#pragma unroll
                for (int i = 0; i < 4; ++i)
                    vi[i] = ld2_sc1(inrow + kb + (i << 7));
            }
#pragma unroll
            for (int i = 0; i < 4; ++i)
                *(float2*)&ldsA[w][kb + (i << 7)] = vi[i];
        }
        __syncthreads();
        // in-half partial accs, packed (overlaps peers finishing B(t-1))
        float2 pA0[8], pA1[8], pA2[8], pA3[8];
#pragma unroll
        for (int bi = 0; bi < 8; ++bi) {
            float2 q0 = {0.f, 0.f}, q1 = {0.f, 0.f}, q2 = {0.f, 0.f}, q3 = {0.f, 0.f};
#pragma unroll
            for (int i = 0; i < 4; ++i) {
                const float2 v = *(const float2*)&ldsA[bi][kb + (i << 7)];
                q0 = pkfma(v, wg[0][i], q0);
                q1 = pkfma(v, wg[1][i], q1);
                q2 = pkfma(v, wg[2][i], q2);
                q3 = pkfma(v, wg[3][i], q3);
            }
            pA0[bi] = q0; pA1[bi] = q1; pA2[bi] = q2; pA3[bi] = q3;
        }
        // wait end-of-B(t-1): h(t) complete, rh/uu(t-1) fully consumed
        if (t > 0) poll_slots<1>(myslots, 2 * t);
        {   // stage h-half of batch b0+w (fresh after wait)
            const int b = b0 + w;
            const float* hrow = hl + (size_t)b * HH;
            float2 vh[4];
            if (fb) {
#pragma unroll
                for (int i = 0; i < 4; ++i)
                    vh[i] = ld2_sc1(hrow + kb + (i << 7));
            } else {
                ld2_sc0_x4(hrow + kb, hrow + kb + 128, hrow + kb + 256,
                           hrow + kb + 384, vh[0], vh[1], vh[2], vh[3]);
            }
#pragma unroll
            for (int i = 0; i < 4; ++i)
                *(float2*)&ldsA[w][512 + kb + (i << 7)] = vh[i];
        }
        __syncthreads();
#pragma unroll
        for (int bi = 0; bi < 8; ++bi) {
            float2 q0 = pA0[bi], q1 = pA1[bi], q2 = pA2[bi], q3 = pA3[bi];
#pragma unroll
            for (int i = 4; i < 8; ++i) {
                const float2 v = *(const float2*)&ldsA[bi][kb + (i << 7)];
                q0 = pkfma(v, wg[0][i], q0);
                q1 = pkfma(v, wg[1][i], q1);
                q2 = pkfma(v, wg[2][i], q2);
                q3 = pkfma(v, wg[3][i], q3);
            }
            const float sum = red4(q0.x + q0.y, q1.x + q1.y,
                                   q2.x + q2.y, q3.x + q3.y, lane);
            if (lane < 4) {
                const int j = gj0 + lane;
                const int b = b0 + bi;
                const float gg = 1.0f / (1.0f + __expf(-(sum + bgj)));
                if (gj0 < HH) {
                    const float val = gg * ldsA[bi][512 + j];
                    if (fb) st1_sc1(rhl + (size_t)b * HH + j, val);
                    else rhl[(size_t)b * HH + j] = val;
                } else {
                    if (fb) st1_sc1(uul + (size_t)b * HH + (j - HH), gg);
                    else uul[(size_t)b * HH + (j - HH)] = gg;
                }
            }
        }
        arrive(&myslots[slot], 2 * t + 1);

        // ================= phase B: candidate + update =================
        // cand x-half partial accs, packed (overlaps peers' A(t))
        float2 pB0[8], pB1[8];
#pragma unroll
        for (int bi = 0; bi < 8; ++bi) {
            float2 q0 = {0.f, 0.f}, q1 = {0.f, 0.f};
#pragma unroll
            for (int i = 0; i < 4; ++i) {
                const float2 v = *(const float2*)&ldsA[bi][kb + (i << 7)];
                q0 = pkfma(v, wc[0][i], q0);
                q1 = pkfma(v, wc[1][i], q1);
            }
            pB0[bi] = q0; pB1[bi] = q1;
        }
        // wait end-of-A(t): rh/uu(t) complete, h(t) fully consumed
        poll_slots<1>(myslots, 2 * t + 1);
        // L0 ring gate: L1 consumed y0[t-16] <=> all L1 slots >= 2t-31.
        if (l == 0 && t >= YD) poll_slots<2>(peerslots, 2 * t - 31);
        {   // stage rh row (full, feeds the dot) + u (own 16 cols only)
            const int b = b0 + w;
            const float* rrow = rhl + (size_t)b * HH;
            float2 vr[4];
            if (fb) {
#pragma unroll
                for (int i = 0; i < 4; ++i)
                    vr[i] = ld2_sc1(rrow + kb + (i << 7));
                if (lane < 16)
                    ldsU[w][lane] = ld1f_sc1(uul + (size_t)b * HH + slot * 16 + lane);
            } else {
                ld2_sc0_x4(rrow + kb, rrow + kb + 128, rrow + kb + 256,
                           rrow + kb + 384, vr[0], vr[1], vr[2], vr[3]);
                if (lane < 16)
                    ldsU[w][lane] = ld_sc0f(uul + (size_t)b * HH + slot * 16 + lane);
            }
#pragma unroll
            for (int i = 0; i < 4; ++i)
                *(float2*)&ldsB[w][kb + (i << 7)] = vr[i];
        }
        __syncthreads();
#pragma unroll
        for (int bi = 0; bi < 8; ++bi) {
            float2 q0 = pB0[bi], q1 = pB1[bi];
#pragma unroll
            for (int i = 0; i < 4; ++i) {
                const float2 v = *(const float2*)&ldsB[bi][kb + (i << 7)];
                q0 = pkfma(v, wc[0][i + 4], q0);
                q1 = pkfma(v, wc[1][i + 4], q1);
            }
            const float sum = red2(q0.x + q0.y, q1.x + q1.y, lane);
            if (lane < 2) {
                const int m = cm0 + lane;
                const int b = b0 + bi;
                const float cv = tanhf(sum + bcm);
                const float u = ldsU[bi][w * 2 + lane];
                const float hold = ldsA[bi][512 + m];
                const bool act = t < sl_[bi];
                const float hn = u * hold + (1.0f - u) * cv;
                const float hstore = act ? hn : hold;
                if (fb) st1_sc1(hl + (size_t)b * HH + m, hstore);
                else hl[(size_t)b * HH + m] = hstore;
                const float yv = act ? hn : 0.0f;
                if (l == 0)
                    st1_sc1(y0 + ((size_t)((t & (YD - 1)) * BB + b)) * HH + m, yv);
                else
                    out[((size_t)b * TT + t) * HH + m] = yv;
            }
        }
        arrive(&myslots[slot], 2 * t + 2);
    }
}

extern "C" void kernel_launch(void* const* d_in, const int* in_sizes, int n_in,
                              void* d_out, int out_size, void* d_ws, size_t ws_size,
                              hipStream_t stream) {
    const float* x = (const float*)d_in[0];
    const int* seq_lens = (const int*)d_in[1];
    const float* Wg = (const float*)d_in[2];
    const float* bg = (const float*)d_in[3];
    const float* Wc = (const float*)d_in[4];
    const float* bc = (const float*)d_in[5];
    float* out = (float*)d_out;
    float* ws = (float*)d_ws;

    // zero h0/h1 + ctrl + prologue tree + slots every launch
    (void)hipMemsetAsync(ws, 0, 33280 * sizeof(float), stream);

    rnn_persist<<<NBLK, NTHR, 0, stream>>>(x, seq_lens, Wg, bg, Wc, bc, out, ws);
}

// Round 15
// 5761.799 us; speedup vs baseline: 1.4030x; 1.0045x over previous
//
#include <hip/hip_runtime.h>
#include <cstddef>

#define BB 32
#define TT 512
#define HH 512
#define NBLK 256
#define NTHR 512
#define YD 16  // y0 ring depth
#define AG __HIP_MEMORY_SCOPE_AGENT

// ---------------------------------------------------------------------------
// Persistent GRU, round 14 = round 13 (best verified: 5.79 ms) with ONE
// change: own-group barrier flags move into the XCD-local L2.
//   Arrive: __syncthreads (vmcnt drain -> all data stores committed), then
//     tid0 stores the phase number to the LOCAL slot (plain store, dirty in
//     this XCD's L2) AND the GLOBAL slot (sc1, L3 — cross-XCD truth).
//   Own-group poll: lane L spins on local slot[L] via sc0 (L2 hit, ~3x
//     faster detect than L3); every 8th spin maxes in the global sc1 value
//     (graceful degradation, no deadlock if local path is ever stale).
//   Peer gates: pure sc1 global polls (unchanged — cross-XCD).
//   Everything else byte-identical to round 13: packed v_pk_fma_f32 dots,
//   split-phase overlap, slot-as-progress protocol, sc0/sc1 data protocol,
//   XCC self-org + all-sc1 fallback.
//
// ws (floats): h0@0[16384] h1@16384[16384] ctrl(int)@32768[64]
//   barb(int)@32832[192] gslot(int)@33024[8*32] lslot(int)@33280[8*32]
//   (zero region ends @33536)
//   y0@36864[16][32][512] rh@299008[2][32][512] uu@331776[2][32][512]
// ---------------------------------------------------------------------------

__device__ __forceinline__ float2 ld2_sc1(const float* p) {
    double d = __hip_atomic_load((const double*)p, __ATOMIC_RELAXED, AG);
    return __builtin_bit_cast(float2, d);
}
__device__ __forceinline__ float ld1f_sc1(const float* p) {
    return __hip_atomic_load(p, __ATOMIC_RELAXED, AG);
}
__device__ __forceinline__ void st1_sc1(float* p, float v) {
    __hip_atomic_store(p, v, __ATOMIC_RELAXED, AG);
}
__device__ __forceinline__ int ldi_sc1(const int* p) {
    return __hip_atomic_load(p, __ATOMIC_RELAXED, AG);
}
__device__ __forceinline__ void sti_sc1(int* p, int v) {
    __hip_atomic_store(p, v, __ATOMIC_RELAXED, AG);
}
// Plain store: dirty in the local XCD L2 (round-6 data-store mechanism).
__device__ __forceinline__ void sti_plain(int* p, int v) {
    asm volatile("global_store_dword %0, %1, off" : : "v"(p), "v"(v) : "memory");
}
// L1-bypassing scalar int load served by the local L2 (round-6 proven).
__device__ __forceinline__ int ldi_sc0(const int* p) {
    int r;
    asm volatile("global_load_dword %0, %1, off sc0\n\ts_waitcnt vmcnt(0)"
                 : "=v"(r) : "v"(p) : "memory");
    return r;
}

// Packed f32 FMA: d = a*b + c on both halves, one instruction (CDNA2+).
__device__ __forceinline__ float2 pkfma(float2 a, float2 b, float2 c) {
    float2 d;
    asm("v_pk_fma_f32 %0, %1, %2, %3" : "=v"(d) : "v"(a), "v"(b), "v"(c));
    return d;
}

// Scalar float load, L1-bypass / local-L2 hit (round-6 proven mechanism).
__device__ __forceinline__ float ld_sc0f(const float* p) {
    float r;
    asm volatile("global_load_dword %0, %1, off sc0\n\ts_waitcnt vmcnt(0)"
                 : "=v"(r) : "v"(p) : "memory");
    return r;
}

// Four 8B loads, L1-bypass / local-L2 hit (round-6 proven).
__device__ __forceinline__ void ld2_sc0_x4(const float* p0, const float* p1,
                                           const float* p2, const float* p3,
                                           float2& v0, float2& v1,
                                           float2& v2, float2& v3) {
    asm volatile(
        "global_load_dwordx2 %0, %4, off sc0\n\t"
        "global_load_dwordx2 %1, %5, off sc0\n\t"
        "global_load_dwordx2 %2, %6, off sc0\n\t"
        "global_load_dwordx2 %3, %7, off sc0\n\t"
        "s_waitcnt vmcnt(0)"
        : "=v"(v0), "=v"(v1), "=v"(v2), "=v"(v3)
        : "v"(p0), "v"(p1), "v"(p2), "v"(p3)
        : "memory");
}

// Reduce 4 accs over 64 lanes; lane ends with total of acc[lane&3].
__device__ __forceinline__ float red4(float a0, float a1, float a2, float a3,
                                      int lane) {
    const bool b1 = lane & 1, b2 = lane & 2;
    float p0 = (b1 ? a1 : a0) + __shfl_xor((b1 ? a0 : a1), 1, 64);
    float p1 = (b1 ? a3 : a2) + __shfl_xor((b1 ? a2 : a3), 1, 64);
    float r = (b2 ? p1 : p0) + __shfl_xor((b2 ? p0 : p1), 2, 64);
    r += __shfl_xor(r, 4, 64);
    r += __shfl_xor(r, 8, 64);
    r += __shfl_xor(r, 16, 64);
    r += __shfl_xor(r, 32, 64);
    return r;
}
// Reduce 2 accs; lane ends with total of acc[lane&1].
__device__ __forceinline__ float red2(float a0, float a1, int lane) {
    const bool b1 = lane & 1;
    float r = (b1 ? a1 : a0) + __shfl_xor((b1 ? a0 : a1), 1, 64);
    r += __shfl_xor(r, 2, 64);
    r += __shfl_xor(r, 4, 64);
    r += __shfl_xor(r, 8, 64);
    r += __shfl_xor(r, 16, 64);
    r += __shfl_xor(r, 32, 64);
    return r;
}

// Global 2-level tree barrier (sc1 RMW) - prologue / self-org only (proven).
__device__ __forceinline__ void gbar(int* barb, int bid, int nbar) {
    __syncthreads();
    if (threadIdx.x == 0) {
        __hip_atomic_fetch_add(&barb[(bid & 31) * 4], 1, __ATOMIC_RELAXED, AG);
        if (bid < 32) {
            const int lt = nbar * 8;
            while (__hip_atomic_load(&barb[bid * 4], __ATOMIC_RELAXED, AG) < lt)
                __builtin_amdgcn_s_sleep(1);
            __hip_atomic_fetch_add(&barb[128], 1, __ATOMIC_RELAXED, AG);
        }
        const int rt = nbar * 32;
        while (__hip_atomic_load(&barb[128], __ATOMIC_RELAXED, AG) < rt)
            __builtin_amdgcn_s_sleep(1);
    }
    __syncthreads();
}

// PEER poll: pure sc1 ballot over the peer group's 32 global slots.
template <int SLP>
__device__ __forceinline__ void poll_peer(int* slots, int need) {
    if (threadIdx.x < 64) {
        for (;;) {
            const int v = ldi_sc1(&slots[threadIdx.x & 31]);
            if (__ballot(v >= need) == ~0ull) break;
            __builtin_amdgcn_s_sleep(SLP);
        }
    }
    __syncthreads();
}

// OWN poll: local-L2 sc0 fast path + periodic sc1 global truth mix-in.
template <int SLP>
__device__ __forceinline__ void poll_own(int* lown, int* gown, int need, int fb) {
    if (threadIdx.x < 64) {
        const int L = threadIdx.x & 31;
        int spins = 0;
        for (;;) {
            int v;
            if (fb) {
                v = ldi_sc1(&gown[L]);
            } else {
                v = ldi_sc0(&lown[L]);
                if ((spins & 7) == 7) {
                    const int gv = ldi_sc1(&gown[L]);
                    v = v > gv ? v : gv;
                }
            }
            if (__ballot(v >= need) == ~0ull) break;
            ++spins;
            __builtin_amdgcn_s_sleep(SLP);
        }
    }
    __syncthreads();
}

// Arrive: drain block stores, then dual flag store (local plain + global sc1).
__device__ __forceinline__ void arrive(int* lslot, int* gslot, int val, int fb) {
    __syncthreads();  // compiler drains vmcnt(0) before s_barrier
    if (threadIdx.x == 0) {
        if (!fb) sti_plain(lslot, val);
        sti_sc1(gslot, val);
    }
}

__global__ __launch_bounds__(NTHR, 2) void rnn_persist(
    const float* __restrict__ x, const int* __restrict__ seq_lens,
    const float* __restrict__ Wg, const float* __restrict__ bg,
    const float* __restrict__ Wc, const float* __restrict__ bc,
    float* __restrict__ out, float* __restrict__ ws) {
    __shared__ float ldsA[8][1024];  // per batch: [input 512 | h 512]
    __shared__ float ldsB[8][512];   // rh rows
    __shared__ float ldsU[8][16];    // u, block's own 16 cand cols only
    __shared__ int shi[4];

    float* h0 = ws;
    float* h1 = ws + 16384;
    int* ctrl = (int*)(ws + 32768);   // pools[16], order@16, fb@17, map@18..33
    int* barb = (int*)(ws + 32832);   // global tree (prologue only)
    int* gslot = (int*)(ws + 33024);  // 8 groups x 32 ints (sc1 truth)
    int* lslot = (int*)(ws + 33280);  // 8 groups x 32 ints (local fast path)
    float* y0 = ws + 36864;           // [YD][BB][HH]
    float* rh = ws + 299008;
    float* uu = ws + 331776;

    const int tid = threadIdx.x, bid = blockIdx.x;
    const int w = tid >> 6, lane = tid & 63;

    // ---- self-organization by physical XCD (rounds 6/8/13 proven) ----
    if (tid == 0) {
        int xcc;
        asm volatile("s_getreg_b32 %0, hwreg(HW_REG_XCC_ID)" : "=s"(xcc));
        xcc &= 15;
        int slot = __hip_atomic_fetch_add(&ctrl[xcc], 1, __ATOMIC_RELAXED, AG);
        shi[0] = xcc; shi[1] = slot;
    }
    __syncthreads();
    gbar(barb, bid, 1);
    if (tid == 0) {
        if (ldi_sc1(&ctrl[shi[0]]) != 32)
            sti_sc1(&ctrl[17], 1);
        if (shi[1] == 0) {
            int ord = __hip_atomic_fetch_add(&ctrl[16], 1, __ATOMIC_RELAXED, AG);
            sti_sc1(&ctrl[18 + shi[0]], ord + 1);
        }
    }
    gbar(barb, bid, 2);
    if (tid == 0) {
        int fbf = ldi_sc1(&ctrl[17]);
        if (ldi_sc1(&ctrl[16]) != 8) fbf = 1;
        int xi, sl;
        if (fbf) { xi = bid & 7; sl = bid >> 3; }
        else     { xi = ldi_sc1(&ctrl[18 + shi[0]]) - 1; sl = shi[1]; }
        shi[2] = fbf; shi[3] = xi; shi[1] = sl;
    }
    __syncthreads();
    const int fb = shi[2];
    const int xcd = shi[3];   // logical group id 0..7
    const int slot = shi[1];  // 0..31 within group
    const int l = xcd & 1;
    const int g = xcd >> 1;
    const int b0 = g * 8;
    const int gj0 = slot * 32 + w * 4;
    const int cm0 = slot * 16 + w * 2;
    const int kb = 2 * lane;

    float* __restrict__ hl = l ? h1 : h0;
    float* __restrict__ rhl = rh + (size_t)l * (BB * HH);
    float* __restrict__ uul = uu + (size_t)l * (BB * HH);
    int* gmy = gslot + xcd * 32;
    int* lmy = lslot + xcd * 32;
    int* peerslots = gslot + (g * 2 + (1 - l)) * 32;

    // ---- one-time weight load into registers (original layout) ----
    float2 wg[4][8];
#pragma unroll
    for (int c = 0; c < 4; ++c)
#pragma unroll
        for (int i = 0; i < 8; ++i) {
            const size_t r = (size_t)l * 1024 + kb + (i << 7);
            wg[c][i].x = Wg[r * 1024 + gj0 + c];
            wg[c][i].y = Wg[(r + 1) * 1024 + gj0 + c];
        }
    float2 wc[2][8];
#pragma unroll
    for (int c = 0; c < 2; ++c)
#pragma unroll
        for (int i = 0; i < 8; ++i) {
            const size_t r = (size_t)l * 1024 + kb + (i << 7);
            wc[c][i].x = Wc[r * 512 + cm0 + c];
            wc[c][i].y = Wc[(r + 1) * 512 + cm0 + c];
        }
    const float bgj = bg[l * 1024 + gj0 + (lane & 3)];
    const float bcm = bc[l * 512 + cm0 + (lane & 1)];
    int sl_[8];
#pragma unroll
    for (int i = 0; i < 8; ++i) sl_[i] = seq_lens[b0 + i];

    for (int t = 0; t < TT; ++t) {
        // ================= phase A: gates =================
        // L1 gate: y0[t] produced <=> all L0 slots >= 2t+2 (L0 arrived B(t)).
        if (l == 1) poll_peer<2>(peerslots, 2 * t + 2);
        {   // stage in-row of batch b0+w (no group dependency)
            const int b = b0 + w;
            const float* inrow = l ? (y0 + ((size_t)((t & (YD - 1)) * BB + b)) * HH)
                                   : (x + ((size_t)b * TT + t) * HH);
            float2 vi[4];
            if (l == 0) {
#pragma unroll
                for (int i = 0; i < 4; ++i)
                    vi[i] = *(const float2*)(inrow + kb + (i << 7));
            } else {
#pragma unroll
                for (int i = 0; i < 4; ++i)
                    vi[i] = ld2_sc1(inrow + kb + (i << 7));
            }
#pragma unroll
            for (int i = 0; i < 4; ++i)
                *(float2*)&ldsA[w][kb + (i << 7)] = vi[i];
        }
        __syncthreads();
        // in-half partial accs, packed (overlaps peers finishing B(t-1))
        float2 pA0[8], pA1[8], pA2[8], pA3[8];
#pragma unroll
        for (int bi = 0; bi < 8; ++bi) {
            float2 q0 = {0.f, 0.f}, q1 = {0.f, 0.f}, q2 = {0.f, 0.f}, q3 = {0.f, 0.f};
#pragma unroll
            for (int i = 0; i < 4; ++i) {
                const float2 v = *(const float2*)&ldsA[bi][kb + (i << 7)];
                q0 = pkfma(v, wg[0][i], q0);
                q1 = pkfma(v, wg[1][i], q1);
                q2 = pkfma(v, wg[2][i], q2);
                q3 = pkfma(v, wg[3][i], q3);
            }
            pA0[bi] = q0; pA1[bi] = q1; pA2[bi] = q2; pA3[bi] = q3;
        }
        // wait end-of-B(t-1): h(t) complete, rh/uu(t-1) fully consumed
        if (t > 0) poll_own<1>(lmy, gmy, 2 * t, fb);
        {   // stage h-half of batch b0+w (fresh after wait)
            const int b = b0 + w;
            const float* hrow = hl + (size_t)b * HH;
            float2 vh[4];
            if (fb) {
#pragma unroll
                for (int i = 0; i < 4; ++i)
                    vh[i] = ld2_sc1(hrow + kb + (i << 7));
            } else {
                ld2_sc0_x4(hrow + kb, hrow + kb + 128, hrow + kb + 256,
                           hrow + kb + 384, vh[0], vh[1], vh[2], vh[3]);
            }
#pragma unroll
            for (int i = 0; i < 4; ++i)
                *(float2*)&ldsA[w][512 + kb + (i << 7)] = vh[i];
        }
        __syncthreads();
#pragma unroll
        for (int bi = 0; bi < 8; ++bi) {
            float2 q0 = pA0[bi], q1 = pA1[bi], q2 = pA2[bi], q3 = pA3[bi];
#pragma unroll
            for (int i = 4; i < 8; ++i) {
                const float2 v = *(const float2*)&ldsA[bi][kb + (i << 7)];
                q0 = pkfma(v, wg[0][i], q0);
                q1 = pkfma(v, wg[1][i], q1);
                q2 = pkfma(v, wg[2][i], q2);
                q3 = pkfma(v, wg[3][i], q3);
            }
            const float sum = red4(q0.x + q0.y, q1.x + q1.y,
                                   q2.x + q2.y, q3.x + q3.y, lane);
            if (lane < 4) {
                const int j = gj0 + lane;
                const int b = b0 + bi;
                const float gg = 1.0f / (1.0f + __expf(-(sum + bgj)));
                if (gj0 < HH) {
                    const float val = gg * ldsA[bi][512 + j];
                    if (fb) st1_sc1(rhl + (size_t)b * HH + j, val);
                    else rhl[(size_t)b * HH + j] = val;
                } else {
                    if (fb) st1_sc1(uul + (size_t)b * HH + (j - HH), gg);
                    else uul[(size_t)b * HH + (j - HH)] = gg;
                }
            }
        }
        arrive(&lmy[slot], &gmy[slot], 2 * t + 1, fb);

        // ================= phase B: candidate + update =================
        // cand x-half partial accs, packed (overlaps peers' A(t))
        float2 pB0[8], pB1[8];
#pragma unroll
        for (int bi = 0; bi < 8; ++bi) {
            float2 q0 = {0.f, 0.f}, q1 = {0.f, 0.f};
#pragma unroll
            for (int i = 0; i < 4; ++i) {
                const float2 v = *(const float2*)&ldsA[bi][kb + (i << 7)];
                q0 = pkfma(v, wc[0][i], q0);
                q1 = pkfma(v, wc[1][i], q1);
            }
            pB0[bi] = q0; pB1[bi] = q1;
        }
        // wait end-of-A(t): rh/uu(t) complete, h(t) fully consumed
        poll_own<1>(lmy, gmy, 2 * t + 1, fb);
        // L0 ring gate: L1 consumed y0[t-16] <=> all L1 slots >= 2t-31.
        if (l == 0 && t >= YD) poll_peer<2>(peerslots, 2 * t - 31);
        {   // stage rh row (full, feeds the dot) + u (own 16 cols only)
            const int b = b0 + w;
            const float* rrow = rhl + (size_t)b * HH;
            float2 vr[4];
            if (fb) {
#pragma unroll
                for (int i = 0; i < 4; ++i)
                    vr[i] = ld2_sc1(rrow + kb + (i << 7));
                if (lane < 16)
                    ldsU[w][lane] = ld1f_sc1(uul + (size_t)b * HH + slot * 16 + lane);
            } else {
                ld2_sc0_x4(rrow + kb, rrow + kb + 128, rrow + kb + 256,
                           rrow + kb + 384, vr[0], vr[1], vr[2], vr[3]);
                if (lane < 16)
                    ldsU[w][lane] = ld_sc0f(uul + (size_t)b * HH + slot * 16 + lane);
            }
#pragma unroll
            for (int i = 0; i < 4; ++i)
                *(float2*)&ldsB[w][kb + (i << 7)] = vr[i];
        }
        __syncthreads();
#pragma unroll
        for (int bi = 0; bi < 8; ++bi) {
            float2 q0 = pB0[bi], q1 = pB1[bi];
#pragma unroll
            for (int i = 0; i < 4; ++i) {
                const float2 v = *(const float2*)&ldsB[bi][kb + (i << 7)];
                q0 = pkfma(v, wc[0][i + 4], q0);
                q1 = pkfma(v, wc[1][i + 4], q1);
            }
            const float sum = red2(q0.x + q0.y, q1.x + q1.y, lane);
            if (lane < 2) {
                const int m = cm0 + lane;
                const int b = b0 + bi;
                const float cv = tanhf(sum + bcm);
                const float u = ldsU[bi][w * 2 + lane];
                const float hold = ldsA[bi][512 + m];
                const bool act = t < sl_[bi];
                const float hn = u * hold + (1.0f - u) * cv;
                const float hstore = act ? hn : hold;
                if (fb) st1_sc1(hl + (size_t)b * HH + m, hstore);
                else hl[(size_t)b * HH + m] = hstore;
                const float yv = act ? hn : 0.0f;
                if (l == 0)
                    st1_sc1(y0 + ((size_t)((t & (YD - 1)) * BB + b)) * HH + m, yv);
                else
                    out[((size_t)b * TT + t) * HH + m] = yv;
            }
        }
        arrive(&lmy[slot], &gmy[slot], 2 * t + 2, fb);
    }
}

extern "C" void kernel_launch(void* const* d_in, const int* in_sizes, int n_in,
                              void* d_out, int out_size, void* d_ws, size_t ws_size,
                              hipStream_t stream) {
    const float* x = (const float*)d_in[0];
    const int* seq_lens = (const int*)d_in[1];
    const float* Wg = (const float*)d_in[2];
    const float* bg = (const float*)d_in[3];
    const float* Wc = (const float*)d_in[4];
    const float* bc = (const float*)d_in[5];
    float* out = (float*)d_out;
    float* ws = (float*)d_ws;

    // zero h0/h1 + ctrl + prologue tree + both slot arrays every launch
    (void)hipMemsetAsync(ws, 0, 33536 * sizeof(float), stream);

    rnn_persist<<<NBLK, NTHR, 0, stream>>>(x, seq_lens, Wg, bg, Wc, bc, out, ws);
}